// Round 3
// baseline (121.439 us; speedup 1.0000x reference)
//
#include <hip/hip_runtime.h>
#include <math.h>

#define BB   8
#define CC   256
#define HH   56
#define WW   56
#define KK   3
#define MIDN 51
#define NTAP (KK*KK)          // 9
#define CKK  (CC*NTAP)        // 2304
#define HW   (HH*WW)          // 3136
#define SPIX 64               // pixels per K1 strip
#define NSTR (HW/SPIX)        // 49 strips, exact
#define CPR  128              // channels per K1 round (2 rounds)
#define XSTR 65               // K1 LDS tile stride: bank (c+p)%32, <=2 lanes/bank
#define NCPB 4                // channels per ddf block
#define TROW 68               // K3 tile row stride (17 float4, bank-rotating)
#define TPL  (58*TROW)        // 3944 floats per halo plane

// ============ K1: sf (full channel reduction + norm) + pooled-mean partials ============
// grid: BB*NSTR = 392 blocks, 256 threads. Each block owns 64 pixels and ALL 256
// channels (2 rounds of 128 through LDS). Writes sf directly (normalized).
__global__ __launch_bounds__(256) void k_sf(const float* __restrict__ x,
                                            const float* __restrict__ ws,
                                            const float* __restrict__ bs,
                                            float* __restrict__ sf,
                                            float* __restrict__ poolpart) {
    int blk = blockIdx.x;
    int s = blk % NSTR;
    int b = blk / NSTR;
    int t = threadIdx.x;
    int p = t & 63;           // pixel within strip
    int q = t >> 6;           // channel quarter (32 channels per round)
    __shared__ float xs[CPR * XSTR];          // [128 ch][65] = 33.3 KB
    __shared__ float wss[NTAP][CC];           // 9 KB
    __shared__ float accq[NTAP * 4 * SPIX];   // 9 KB
    for (int idx = t; idx < NTAP * CC; idx += 256)
        ((float*)wss)[idx] = ws[idx];         // ws is (9,256) row-major
    float acc[NTAP];
    #pragma unroll
    for (int n = 0; n < NTAP; ++n) acc[n] = 0.f;
    const float* xb = x + ((size_t)b * CC) * HW + s * SPIX;
    #pragma unroll
    for (int r = 0; r < 2; ++r) {
        if (r) __syncthreads();               // round-0 readers done before restage
        // stage 32 channels per thread: load to regs, then LDS (transposed)
        float vv[32];
        #pragma unroll
        for (int c = 0; c < 32; ++c)
            vv[c] = xb[(size_t)(r * CPR + q * 32 + c) * HW + p];
        #pragma unroll
        for (int c = 0; c < 32; ++c)
            xs[(q * 32 + c) * XSTR + p] = vv[c];
        __syncthreads();
        // pool: per-channel sum over the 64 strip pixels (threads 0..127)
        if (t < CPR) {
            float sum = 0.f;
            #pragma unroll 8
            for (int pp = 0; pp < SPIX; ++pp) sum += xs[t * XSTR + pp];
            poolpart[((size_t)(b * NSTR + s)) * CC + r * CPR + t] = sum;
        }
        // dot: 32 channels x 9 taps per thread
        #pragma unroll 4
        for (int c = 0; c < 32; ++c) {
            float xv = xs[(q * 32 + c) * XSTR + p];
            #pragma unroll
            for (int n = 0; n < NTAP; ++n)
                acc[n] += xv * wss[n][r * CPR + q * 32 + c];
        }
    }
    #pragma unroll
    for (int n = 0; n < NTAP; ++n) accq[(n * 4 + q) * SPIX + p] = acc[n];
    __syncthreads();
    if (t < SPIX) {
        float y[NTAP];
        #pragma unroll
        for (int n = 0; n < NTAP; ++n) {
            float v = bs[n];
            #pragma unroll
            for (int qq = 0; qq < 4; ++qq) v += accq[(n * 4 + qq) * SPIX + t];
            y[n] = v;
        }
        float mean = 0.f;
        #pragma unroll
        for (int n = 0; n < NTAP; ++n) mean += y[n];
        mean *= (1.f / NTAP);
        float var = 0.f;
        #pragma unroll
        for (int n = 0; n < NTAP; ++n) { float d = y[n] - mean; var += d * d; }
        float inv = 0.47140452079103173f /    // GAIN/K = sqrt(2)/3
                    (sqrtf(var * (1.f / (NTAP - 1))) + 1e-10f);
        #pragma unroll
        for (int n = 0; n < NTAP; ++n)
            sf[((size_t)(b * NTAP + n)) * HW + s * SPIX + t] = (y[n] - mean) * inv;
    }
}

// ============ K2: MLP + cf only ============
#define MLPBLK (BB*8)                 // 64 blocks: (batch, 32-channel chunk)
#define CPC 32
#define W2CHUNK (CPC*NTAP*MIDN)       // 14688 floats per 32-channel chunk
__global__ __launch_bounds__(256) void k_mlp(const float* __restrict__ poolpart,
                                             const float* __restrict__ w1,
                                             const float* __restrict__ b1,
                                             const float* __restrict__ w2,
                                             const float* __restrict__ b2,
                                             const float* __restrict__ fn_std,
                                             float* __restrict__ cf) {
    __shared__ float smem[W2CHUNK + 256 + 64 + CPC * NTAP];  // 61.2 KB
    float* w2s = smem;                    // [14688]
    float* ps  = smem + W2CHUNK;          // [256]
    float* y1  = ps + 256;                // [64] (51 used)
    float* y2s = y1 + 64;                 // [288]
    int blk = blockIdx.x;
    int t = threadIdx.x;
    int b = blk >> 3, chunk = blk & 7;
    int c0 = chunk * CPC;
    const float4* w2v = (const float4*)(w2 + (size_t)chunk * W2CHUNK);
    float4* w2s4 = (float4*)w2s;
    for (int i = t; i < W2CHUNK / 4; i += 256) w2s4[i] = w2v[i];
    {
        float s = 0.f;
        const float* pp = poolpart + ((size_t)b * NSTR) * CC + t;
        for (int st = 0; st < NSTR; ++st) s += pp[(size_t)st * CC];
        ps[t] = s * (1.0f / HW);
    }
    __syncthreads();
    if (t < MIDN) {
        float acc = b1[t];
        const float* wr = w1 + t * CC;
        for (int c2 = 0; c2 < CC; ++c2) acc += ps[c2] * wr[c2];
        y1[t] = fmaxf(acc, 0.f);
    }
    __syncthreads();
    #pragma unroll
    for (int base = 0; base < 512; base += 256) {
        int idx = base + t;                       // idx = cl*9+q
        if (idx < CPC * NTAP) {
            float acc = b2[c0 * NTAP + idx];
            const float* r = w2s + idx * MIDN;
            #pragma unroll 3
            for (int m = 0; m < MIDN; ++m) acc += y1[m] * r[m];
            y2s[idx] = acc;
        }
    }
    __syncthreads();
    if (t < CPC) {
        int c = c0 + t;
        float y2[NTAP];
        #pragma unroll
        for (int qq = 0; qq < NTAP; ++qq) y2[qq] = y2s[t * NTAP + qq];
        float mean = 0.f;
        #pragma unroll
        for (int qq = 0; qq < NTAP; ++qq) mean += y2[qq];
        mean *= (1.f / NTAP);
        float var = 0.f;
        #pragma unroll
        for (int qq = 0; qq < NTAP; ++qq) { float d = y2[qq] - mean; var += d * d; }
        float inv = 1.f / (sqrtf(var * (1.f / (NTAP - 1))) + 1e-10f);
        #pragma unroll
        for (int qq = 0; qq < NTAP; ++qq) {
            int idx = c * NTAP + qq;
            cf[(size_t)b * CKK + idx] = (y2[qq] - mean) * inv * fn_std[idx];
        }
    }
}

// ============ K3: DDF apply — register-sliding row segments ============
// 448 threads = 56 rows x 8 segments x 7 pixels (exact, no tail).
// Tile: [58 rows][TROW=68], x row r col m -> xt[k][(r+1)*68 + m+4]; halo zeros.
// Per (u,channel): ONE 9-float register window serves 7 outputs ->
// compute LDS reads 108/thread (vs 221 scalar before); staging/zero are b128.
// LDS 63.1 KB -> 2 blocks/CU, 14 waves/CU. VGPR ~110 < 128 cap.
__global__ __launch_bounds__(448) void k_ddf(const float* __restrict__ x,
                                             const float* __restrict__ cf,
                                             const float* __restrict__ sf,
                                             float* __restrict__ out) {
    int blk = blockIdx.x;
    int b = blk / (CC / NCPB), cg = blk % (CC / NCPB);
    int c0 = cg * NCPB;
    int t = threadIdx.x;
    __shared__ __align__(16) float xt[NCPB][TPL];   // 63.1 KB
    {
        float4 z4 = make_float4(0.f, 0.f, 0.f, 0.f);
        float4* xt4 = (float4*)xt;
        for (int i4 = t; i4 < NCPB * TPL / 4; i4 += 448) xt4[i4] = z4;
    }
    __syncthreads();
    const float4* xp4 = (const float4*)(x + ((size_t)(b * CC + c0)) * HW);
    for (int i4 = t; i4 < NCPB * HW / 4; i4 += 448) {   // 3136 = 7*448 exact
        float4 v = xp4[i4];
        int k = i4 / (HW / 4);
        int rem4 = i4 - k * (HW / 4);
        int r = rem4 / (WW / 4);
        int col = 4 * (rem4 - r * (WW / 4));
        *(float4*)&xt[k][(r + 1) * TROW + col + 4] = v;
    }
    float cf9[NCPB][NTAP];
    const float* cfp = cf + (size_t)b * CKK + c0 * NTAP;
    #pragma unroll
    for (int k = 0; k < NCPB; ++k)
        #pragma unroll
        for (int n = 0; n < NTAP; ++n) cf9[k][n] = cfp[k * NTAP + n];
    __syncthreads();
    int row = t >> 3;          // 0..55
    int j0 = (t & 7) * 7;      // 0,7,...,49
    const float* sfb = sf + (size_t)b * NTAP * HW + row * WW + j0;
    float acc[NCPB][7];
    #pragma unroll
    for (int k = 0; k < NCPB; ++k)
        #pragma unroll
        for (int jj = 0; jj < 7; ++jj) acc[k][jj] = 0.f;
    #pragma unroll
    for (int u = 0; u < KK; ++u) {
        float sfv[3][7];
        #pragma unroll
        for (int v = 0; v < 3; ++v)
            #pragma unroll
            for (int jj = 0; jj < 7; ++jj)
                sfv[v][jj] = sfb[(size_t)(u * 3 + v) * HW + jj];
        int base = (row + u) * TROW + j0 + 3;      // x col j0-1
        #pragma unroll
        for (int k = 0; k < NCPB; ++k) {
            float xr[9];
            #pragma unroll
            for (int m = 0; m < 9; ++m) xr[m] = xt[k][base + m];
            float c_0 = cf9[k][u * 3 + 0];
            float c_1 = cf9[k][u * 3 + 1];
            float c_2 = cf9[k][u * 3 + 2];
            #pragma unroll
            for (int jj = 0; jj < 7; ++jj)
                acc[k][jj] += xr[jj]     * (c_0 * sfv[0][jj])
                            + xr[jj + 1] * (c_1 * sfv[1][jj])
                            + xr[jj + 2] * (c_2 * sfv[2][jj]);
        }
    }
    float* op = out + ((size_t)(b * CC + c0)) * HW + row * WW + j0;
    #pragma unroll
    for (int k = 0; k < NCPB; ++k)
        #pragma unroll
        for (int jj = 0; jj < 7; ++jj) op[(size_t)k * HW + jj] = acc[k][jj];
}

extern "C" void kernel_launch(void* const* d_in, const int* in_sizes, int n_in,
                              void* d_out, int out_size, void* d_ws, size_t ws_size,
                              hipStream_t stream) {
    const float* x      = (const float*)d_in[0];
    const float* w1     = (const float*)d_in[1];
    const float* b1     = (const float*)d_in[2];
    const float* w2     = (const float*)d_in[3];
    const float* b2     = (const float*)d_in[4];
    const float* ws     = (const float*)d_in[5];
    const float* bs     = (const float*)d_in[6];
    const float* fn_std = (const float*)d_in[7];
    float* out = (float*)d_out;

    float* wsf      = (float*)d_ws;
    float* cf       = wsf;                         // BB*CKK           = 18432
    float* sf       = cf + 18432;                  // BB*NTAP*HW       = 225792
    float* poolpart = sf + 225792;                 // BB*NSTR*CC       = 100352

    k_sf<<<BB * NSTR, 256, 0, stream>>>(x, ws, bs, sf, poolpart);
    k_mlp<<<MLPBLK, 256, 0, stream>>>(poolpart, w1, b1, w2, b2, fn_std, cf);
    k_ddf<<<BB * (CC / NCPB), 448, 0, stream>>>(x, cf, sf, out);
}

// Round 4
// 115.036 us; speedup vs baseline: 1.0557x; 1.0557x over previous
//
#include <hip/hip_runtime.h>
#include <math.h>

#define BB   8
#define CC   256
#define HH   56
#define WW   56
#define KK   3
#define MIDN 51
#define NTAP (KK*KK)          // 9
#define CKK  (CC*NTAP)        // 2304
#define HW   (HH*WW)          // 3136
#define SPIX 64               // pixels per K1 strip
#define NSTR (HW/SPIX)        // 49 strips, exact
#define CPR  128              // channels per K1 round (2 rounds)
#define XSTR 65               // K1 LDS tile stride: bank (c+p)%32, <=2 lanes/bank
#define NCPB 4                // channels per ddf block
#define TILE 3364             // 58*58 halo tile (K3)

// ============ K1: sf (full channel reduction + norm) + pooled-mean partials ============
// grid: BB*NSTR = 392 blocks, 256 threads. Each block owns 64 pixels and ALL 256
// channels (2 rounds of 128 through LDS). Writes sf directly (normalized).
__global__ __launch_bounds__(256) void k_sf(const float* __restrict__ x,
                                            const float* __restrict__ ws,
                                            const float* __restrict__ bs,
                                            float* __restrict__ sf,
                                            float* __restrict__ poolpart) {
    int blk = blockIdx.x;
    int s = blk % NSTR;
    int b = blk / NSTR;
    int t = threadIdx.x;
    int p = t & 63;           // pixel within strip
    int q = t >> 6;           // channel quarter (32 channels per round)
    __shared__ float xs[CPR * XSTR];          // [128 ch][65] = 33.3 KB
    __shared__ float wss[NTAP][CC];           // 9 KB
    __shared__ float accq[NTAP * 4 * SPIX];   // 9 KB
    for (int idx = t; idx < NTAP * CC; idx += 256)
        ((float*)wss)[idx] = ws[idx];         // ws is (9,256) row-major
    float acc[NTAP];
    #pragma unroll
    for (int n = 0; n < NTAP; ++n) acc[n] = 0.f;
    const float* xb = x + ((size_t)b * CC) * HW + s * SPIX;
    #pragma unroll
    for (int r = 0; r < 2; ++r) {
        if (r) __syncthreads();               // round-0 readers done before restage
        // stage 32 channels per thread: load to regs, then LDS (transposed)
        float vv[32];
        #pragma unroll
        for (int c = 0; c < 32; ++c)
            vv[c] = xb[(size_t)(r * CPR + q * 32 + c) * HW + p];
        #pragma unroll
        for (int c = 0; c < 32; ++c)
            xs[(q * 32 + c) * XSTR + p] = vv[c];
        __syncthreads();
        // pool: per-channel sum over the 64 strip pixels (threads 0..127)
        if (t < CPR) {
            float sum = 0.f;
            #pragma unroll 8
            for (int pp = 0; pp < SPIX; ++pp) sum += xs[t * XSTR + pp];
            poolpart[((size_t)(b * NSTR + s)) * CC + r * CPR + t] = sum;
        }
        // dot: 32 channels x 9 taps per thread
        #pragma unroll 4
        for (int c = 0; c < 32; ++c) {
            float xv = xs[(q * 32 + c) * XSTR + p];
            #pragma unroll
            for (int n = 0; n < NTAP; ++n)
                acc[n] += xv * wss[n][r * CPR + q * 32 + c];
        }
    }
    #pragma unroll
    for (int n = 0; n < NTAP; ++n) accq[(n * 4 + q) * SPIX + p] = acc[n];
    __syncthreads();
    if (t < SPIX) {
        float y[NTAP];
        #pragma unroll
        for (int n = 0; n < NTAP; ++n) {
            float v = bs[n];
            #pragma unroll
            for (int qq = 0; qq < 4; ++qq) v += accq[(n * 4 + qq) * SPIX + t];
            y[n] = v;
        }
        float mean = 0.f;
        #pragma unroll
        for (int n = 0; n < NTAP; ++n) mean += y[n];
        mean *= (1.f / NTAP);
        float var = 0.f;
        #pragma unroll
        for (int n = 0; n < NTAP; ++n) { float d = y[n] - mean; var += d * d; }
        float inv = 0.47140452079103173f /    // GAIN/K = sqrt(2)/3
                    (sqrtf(var * (1.f / (NTAP - 1))) + 1e-10f);
        #pragma unroll
        for (int n = 0; n < NTAP; ++n)
            sf[((size_t)(b * NTAP + n)) * HW + s * SPIX + t] = (y[n] - mean) * inv;
    }
}

// ============ K2: DDF apply with inline MLP (K2 fused in) ============
// grid: BB*CC/NCPB = 512 blocks, 512 threads. Per block: recompute the batch's
// tiny MLP for its own 4 channels (pooled reduce -> y1 -> y2 -> norm -> cf in
// LDS), overlapped with x halo-tile staging; then the proven scalar ddf loop.
// LDS 53.8 + 1.6 KB -> 2 blocks/CU, 16 waves/CU. Removes the 64-block K2
// dispatch and its serialization bubble.
__global__ __launch_bounds__(512) void k_ddf(const float* __restrict__ x,
                                             const float* __restrict__ poolpart,
                                             const float* __restrict__ w1,
                                             const float* __restrict__ b1,
                                             const float* __restrict__ w2,
                                             const float* __restrict__ b2,
                                             const float* __restrict__ fn_std,
                                             const float* __restrict__ sf,
                                             float* __restrict__ out) {
    int blk = blockIdx.x;
    int b = blk / (CC / NCPB), cg = blk % (CC / NCPB);
    int c0 = cg * NCPB;
    int t = threadIdx.x;
    __shared__ float xt[NCPB][TILE];          // 53.8 KB
    __shared__ float ps[CC];                  // pooled means
    __shared__ float y1s[64];                 // 51 used
    __shared__ float y2s[NCPB * NTAP];        // 36
    __shared__ float cfs[NCPB * NTAP];        // 36
    for (int idx = t; idx < NCPB * TILE; idx += 512) ((float*)xt)[idx] = 0.f;
    __syncthreads();
    // stage 4 contiguous planes with float4 loads (NCPB*HW/4 = 3136 float4s)
    const float4* xp4 = (const float4*)(x + ((size_t)(b * CC + c0)) * HW);
    for (int i4 = t; i4 < NCPB * HW / 4; i4 += 512) {
        float4 v = xp4[i4];
        int k = i4 / (HW / 4);                 // plane
        int rem4 = i4 - k * (HW / 4);          // float4 index within plane
        int r = rem4 / (WW / 4);               // row
        int col = 4 * (rem4 - r * (WW / 4));   // col (multiple of 4)
        float* d = &xt[k][(r + 1) * 58 + col + 1];
        d[0] = v.x; d[1] = v.y; d[2] = v.z; d[3] = v.w;
    }
    // ---- inline MLP (overlaps with staging latency) ----
    if (t < CC) {
        float s = 0.f;
        const float* pp = poolpart + ((size_t)b * NSTR) * CC + t;
        for (int st = 0; st < NSTR; ++st) s += pp[(size_t)st * CC];
        ps[t] = s * (1.0f / HW);
    }
    __syncthreads();
    if (t < MIDN) {
        float a = b1[t];
        const float* wr = w1 + t * CC;
        for (int c2 = 0; c2 < CC; ++c2) a += ps[c2] * wr[c2];
        y1s[t] = fmaxf(a, 0.f);
    }
    __syncthreads();
    if (t < NCPB * NTAP) {
        int row = c0 * NTAP + t;               // (c0+k)*9+q
        float a = b2[row];
        const float* r = w2 + (size_t)row * MIDN;
        #pragma unroll 3
        for (int m = 0; m < MIDN; ++m) a += y1s[m] * r[m];
        y2s[t] = a;
    }
    __syncthreads();
    if (t < NCPB) {
        float y2[NTAP];
        #pragma unroll
        for (int q = 0; q < NTAP; ++q) y2[q] = y2s[t * NTAP + q];
        float mean = 0.f;
        #pragma unroll
        for (int q = 0; q < NTAP; ++q) mean += y2[q];
        mean *= (1.f / NTAP);
        float var = 0.f;
        #pragma unroll
        for (int q = 0; q < NTAP; ++q) { float d = y2[q] - mean; var += d * d; }
        float inv = 1.f / (sqrtf(var * (1.f / (NTAP - 1))) + 1e-10f);
        #pragma unroll
        for (int q = 0; q < NTAP; ++q)
            cfs[t * NTAP + q] = (y2[q] - mean) * inv * fn_std[(c0 + t) * NTAP + q];
    }
    __syncthreads();
    float cf9[NCPB][NTAP];
    #pragma unroll
    for (int k = 0; k < NCPB; ++k)
        #pragma unroll
        for (int n = 0; n < NTAP; ++n) cf9[k][n] = cfs[k * NTAP + n];
    // ---- ddf apply (proven scalar form, coalesced per-pixel mapping) ----
    const float* sfb = sf + (size_t)b * NTAP * HW;
    float* op = out + ((size_t)(b * CC + c0)) * HW;
    for (int idx = t; idx < HW; idx += 512) {
        int i = idx / WW, j = idx - i * WW;
        float s9[NTAP];
        #pragma unroll
        for (int n = 0; n < NTAP; ++n) s9[n] = sfb[(size_t)n * HW + idx];
        float acc[NCPB];
        #pragma unroll
        for (int k = 0; k < NCPB; ++k) acc[k] = 0.f;
        #pragma unroll
        for (int u = 0; u < KK; ++u)
            #pragma unroll
            for (int v = 0; v < KK; ++v) {
                int n = u * KK + v;
                int o = (i + u) * 58 + (j + v);
                #pragma unroll
                for (int k = 0; k < NCPB; ++k)
                    acc[k] += xt[k][o] * (cf9[k][n] * s9[n]);
            }
        #pragma unroll
        for (int k = 0; k < NCPB; ++k) op[(size_t)k * HW + idx] = acc[k];
    }
}

extern "C" void kernel_launch(void* const* d_in, const int* in_sizes, int n_in,
                              void* d_out, int out_size, void* d_ws, size_t ws_size,
                              hipStream_t stream) {
    const float* x      = (const float*)d_in[0];
    const float* w1     = (const float*)d_in[1];
    const float* b1     = (const float*)d_in[2];
    const float* w2     = (const float*)d_in[3];
    const float* b2     = (const float*)d_in[4];
    const float* ws     = (const float*)d_in[5];
    const float* bs     = (const float*)d_in[6];
    const float* fn_std = (const float*)d_in[7];
    float* out = (float*)d_out;

    float* wsf      = (float*)d_ws;
    float* sf       = wsf;                         // BB*NTAP*HW = 225792
    float* poolpart = sf + 225792;                 // BB*NSTR*CC = 100352

    k_sf<<<BB * NSTR, 256, 0, stream>>>(x, ws, bs, sf, poolpart);
    k_ddf<<<BB * (CC / NCPB), 512, 0, stream>>>(x, poolpart, w1, b1, w2, b2,
                                                fn_std, sf, out);
}